// Round 5
// baseline (80.159 us; speedup 1.0000x reference)
//
#include <hip/hip_runtime.h>

#define BB 16
#define QQ 64
#define KK 512
#define DD 256
#define HH 256
#define KSPL 8

#define LOG2E2 2.88539008177792681f   // 2*log2(e): exp2(LOG2E2*x) = e^{2x}

typedef unsigned int uint;
typedef unsigned short ushort;

__device__ __forceinline__ float fast_exp2(float x) {
#if __has_builtin(__builtin_amdgcn_exp2f)
    return __builtin_amdgcn_exp2f(x);
#else
    return exp2f(x);
#endif
}

__device__ __forceinline__ ushort f32_to_bf16_rtne(float x) {
    uint u = __float_as_uint(x);
    u = (u + 0x7FFFu + ((u >> 16) & 1u)) >> 16;
    return (ushort)u;
}

// unpack 8 bf16 (uint4) -> two float4
__device__ __forceinline__ void cvt8(uint4 u, float4& a, float4& b) {
    a.x = __uint_as_float(u.x << 16); a.y = __uint_as_float(u.x & 0xFFFF0000u);
    a.z = __uint_as_float(u.y << 16); a.w = __uint_as_float(u.y & 0xFFFF0000u);
    b.x = __uint_as_float(u.z << 16); b.y = __uint_as_float(u.z & 0xFFFF0000u);
    b.z = __uint_as_float(u.w << 16); b.w = __uint_as_float(u.w & 0xFFFF0000u);
}

// ---------------------------------------------------------------------------
// Both projections, one launch. q-features -> f32 (1MB); k-features -> bf16
// (4MB, halves the scores-kernel stream). Both pre-scaled by 2log2e.
// Key tiles fully beyond valid_len skipped (outputs never consumed).
// ---------------------------------------------------------------------------
__global__ __launch_bounds__(256) void proj_both(
        const float* __restrict__ Xq, const float* __restrict__ Wq, float* __restrict__ Yq,
        const float* __restrict__ Xk, const float* __restrict__ Wk, ushort* __restrict__ Yk16,
        const int* __restrict__ valid_lens) {
    __shared__ float XsT[32][68];
    __shared__ float Ws[32][64];
    const int rt = blockIdx.x;
    const bool is_q = (rt < 16);
    const float* X; const float* W; int row0;
    if (is_q) { X = Xq; W = Wq; row0 = rt * 64; }
    else {
        X = Xk; W = Wk; row0 = (rt - 16) * 64;
        const int bb    = row0 >> 9;
        const int local = row0 & 511;
        if (local >= valid_lens[bb]) return;
    }
    const int col0 = blockIdx.y * 64;
    const int tid = threadIdx.x;
    const int tx = tid & 15, ty = tid >> 4;

    float acc[4][4] = {};

    for (int k0 = 0; k0 < HH; k0 += 32) {
        {
            const int m  = tid >> 3;
            const int kk = (tid & 7) * 4;
            #pragma unroll
            for (int s = 0; s < 2; ++s) {
                float4 x4 = *(const float4*)(X + (size_t)(row0 + m + 32*s) * HH + k0 + kk);
                XsT[kk+0][m+32*s] = x4.x;
                XsT[kk+1][m+32*s] = x4.y;
                XsT[kk+2][m+32*s] = x4.z;
                XsT[kk+3][m+32*s] = x4.w;
            }
        }
        {
            const int kk = tid >> 4;
            const int c  = (tid & 15) * 4;
            #pragma unroll
            for (int s = 0; s < 2; ++s) {
                float4 w4 = *(const float4*)(W + (size_t)(k0 + kk + 16*s) * HH + col0 + c);
                *(float4*)(&Ws[kk+16*s][c]) = w4;
            }
        }
        __syncthreads();
        #pragma unroll
        for (int kk = 0; kk < 32; ++kk) {
            float4 a = *(const float4*)(&XsT[kk][ty*4]);
            float4 b = *(const float4*)(&Ws[kk][tx*4]);
            acc[0][0] += a.x*b.x; acc[0][1] += a.x*b.y; acc[0][2] += a.x*b.z; acc[0][3] += a.x*b.w;
            acc[1][0] += a.y*b.x; acc[1][1] += a.y*b.y; acc[1][2] += a.y*b.z; acc[1][3] += a.y*b.w;
            acc[2][0] += a.z*b.x; acc[2][1] += a.z*b.y; acc[2][2] += a.z*b.z; acc[2][3] += a.z*b.w;
            acc[3][0] += a.w*b.x; acc[3][1] += a.w*b.y; acc[3][2] += a.w*b.z; acc[3][3] += a.w*b.w;
        }
        __syncthreads();
    }
    if (is_q) {
        float* Y = (float*)Yq;
        #pragma unroll
        for (int i = 0; i < 4; ++i) {
            float4 o = make_float4(acc[i][0]*LOG2E2, acc[i][1]*LOG2E2,
                                   acc[i][2]*LOG2E2, acc[i][3]*LOG2E2);
            *(float4*)(Y + (size_t)(row0 + ty*4 + i) * HH + col0 + tx*4) = o;
        }
    } else {
        #pragma unroll
        for (int i = 0; i < 4; ++i) {
            ushort4 o;
            o.x = f32_to_bf16_rtne(acc[i][0]*LOG2E2);
            o.y = f32_to_bf16_rtne(acc[i][1]*LOG2E2);
            o.z = f32_to_bf16_rtne(acc[i][2]*LOG2E2);
            o.w = f32_to_bf16_rtne(acc[i][3]*LOG2E2);
            *(ushort4*)(Yk16 + (size_t)(row0 + ty*4 + i) * HH + col0 + tx*4) = o;
        }
    }
}

// ---------------------------------------------------------------------------
// scores for 4 q rows per block; kfeat in bf16; vl skip + prefetch.
// grid (B, Q/4, KSPL=8), 256 thr (4 waves). Wave strip = 16 k = 4 groups of 4.
// Lane: hg = lane&15 owns h-chunk [hg*16,+16); ksub = lane>>4.
// ---------------------------------------------------------------------------
__global__ __launch_bounds__(256) void scores_kernel(
        const float* __restrict__ qf, const ushort* __restrict__ kf16,
        const float* __restrict__ w_v, const int* __restrict__ valid_lens,
        float* __restrict__ scores) {
    const int b    = blockIdx.x;
    const int q0   = blockIdx.y * 4;
    const int ks   = blockIdx.z;
    const int lane = threadIdx.x & 63;
    const int wave = threadIdx.x >> 6;
    const int hg   = lane & 15;
    const int ksub = lane >> 4;
    const int h0   = hg * 16;

    float4 nw[4];
    float wvsum = 0.f;
    #pragma unroll
    for (int i = 0; i < 4; ++i) {
        float4 w = *(const float4*)(w_v + h0 + i*4);
        wvsum += ((w.x + w.y) + (w.z + w.w));
        nw[i] = make_float4(-2.f*w.x, -2.f*w.y, -2.f*w.z, -2.f*w.w);
    }

    float4 qv[4][4];
    #pragma unroll
    for (int r = 0; r < 4; ++r) {
        const float* qr = qf + (size_t)(b*QQ + q0 + r) * HH + h0;
        #pragma unroll
        for (int i = 0; i < 4; ++i) qv[r][i] = *(const float4*)(qr + i*4);
    }

    const int vl   = valid_lens[b];
    const int base = ks * (KK/KSPL) + wave * 16;
    int rem = vl - base;
    const int ng = (rem <= 0) ? 0 : ((rem >= 16) ? 4 : ((rem + 3) >> 2));

    float* srow0 = scores + (size_t)(b*QQ + q0) * KK;
    const ushort* kptr = kf16 + (size_t)(b*KK + base + ksub) * HH + h0;

    uint4 c0, c1;
    if (ng > 0) {
        c0 = *(const uint4*)(kptr);
        c1 = *(const uint4*)(kptr + 8);
    }

    for (int g = 0; g < ng; ++g) {
        uint4 n0, n1;
        const bool more = (g + 1 < ng);
        if (more) {
            const ushort* kp = kptr + (size_t)(g+1) * 4 * HH;
            n0 = *(const uint4*)(kp);
            n1 = *(const uint4*)(kp + 8);
        }
        float4 kv[4];
        cvt8(c0, kv[0], kv[1]);
        cvt8(c1, kv[2], kv[3]);

        float s[4];
        #pragma unroll
        for (int r = 0; r < 4; ++r) {
            float a0 = wvsum, a1 = 0.f, a2 = 0.f, a3 = 0.f;
            #pragma unroll
            for (int i = 0; i < 4; ++i) {
                float e0 = fast_exp2(qv[r][i].x + kv[i].x);
                float e1 = fast_exp2(qv[r][i].y + kv[i].y);
                float e2 = fast_exp2(qv[r][i].z + kv[i].z);
                float e3 = fast_exp2(qv[r][i].w + kv[i].w);
                a0 = fmaf(nw[i].x, __builtin_amdgcn_rcpf(e0 + 1.f), a0);
                a1 = fmaf(nw[i].y, __builtin_amdgcn_rcpf(e1 + 1.f), a1);
                a2 = fmaf(nw[i].z, __builtin_amdgcn_rcpf(e2 + 1.f), a2);
                a3 = fmaf(nw[i].w, __builtin_amdgcn_rcpf(e3 + 1.f), a3);
            }
            s[r] = (a0 + a1) + (a2 + a3);
        }
        #pragma unroll
        for (int off = 8; off; off >>= 1) {
            #pragma unroll
            for (int r = 0; r < 4; ++r) s[r] += __shfl_xor(s[r], off);
        }
        const int k = base + g*4 + ksub;
        if (hg == 0) {
            const bool ok = (k < vl);
            #pragma unroll
            for (int r = 0; r < 4; ++r)
                srow0[(size_t)r * KK + k] = ok ? s[r] : -1e6f;
        }
        c0 = n0; c1 = n1;
    }
    for (int g = ng; g < 4; ++g) {
        const int k = base + g*4 + ksub;
        if (hg == 0) {
            #pragma unroll
            for (int r = 0; r < 4; ++r) srow0[(size_t)r * KK + k] = -1e6f;
        }
    }
}

// ---------------------------------------------------------------------------
// softmax + PV for 4 q rows per block. grid (B, Q/4), 512 thr (8 waves).
// Softmax: wave w -> row r=w>>1, half h=w&1 (256 k each), LDS combine.
// PV: wave w -> row r=w&3, k parity hs=w>>2 (balanced under vl); 4 waves
// share each V row (L1 broadcast). Cross-wave reduce in LDS.
// ---------------------------------------------------------------------------
__global__ __launch_bounds__(512) void attn_pv_kernel(
        const float* __restrict__ scores, const float* __restrict__ values,
        const int* __restrict__ valid_lens, float* __restrict__ out) {
    __shared__ float ps[4][KK];     // 8 KB
    __shared__ float red[8][DD];    // 8 KB
    __shared__ float wred[16];
    const int b    = blockIdx.x;
    const int q0   = blockIdx.y * 4;
    const int tid  = threadIdx.x;
    const int lane = tid & 63;
    const int w    = tid >> 6;
    const int vl   = valid_lens[b];

    // ---- softmax ----
    {
        const int r = w >> 1, h = w & 1;
        const float* srow = scores + (size_t)(b*QQ + q0 + r) * KK + h*256;
        float4 sv = *(const float4*)(srow + lane*4);
        float m = fmaxf(fmaxf(sv.x, sv.y), fmaxf(sv.z, sv.w));
        #pragma unroll
        for (int off = 32; off; off >>= 1) m = fmaxf(m, __shfl_xor(m, off));
        if (lane == 0) wred[w] = m;
        __syncthreads();
        m = fmaxf(wred[r*2], wred[r*2+1]);

        float e0 = __expf(sv.x - m), e1 = __expf(sv.y - m);
        float e2 = __expf(sv.z - m), e3 = __expf(sv.w - m);
        float sum = (e0 + e1) + (e2 + e3);
        #pragma unroll
        for (int off = 32; off; off >>= 1) sum += __shfl_xor(sum, off);
        if (lane == 0) wred[8 + w] = sum;
        __syncthreads();
        const float inv = 1.f / (wred[8 + r*2] + wred[8 + r*2 + 1]);
        *(float4*)(&ps[r][h*256 + lane*4]) =
            make_float4(e0*inv, e1*inv, e2*inv, e3*inv);
    }
    __syncthreads();

    // ---- PV ----
    {
        const int r  = w & 3;
        const int hs = w >> 2;
        float4 acc = make_float4(0.f, 0.f, 0.f, 0.f);
        const float* V = values + (size_t)b * KK * DD + lane*4;
        for (int k = hs; k < vl; k += 2) {
            const float pw = ps[r][k];
            float4 v4 = *(const float4*)(V + (size_t)k * DD);
            acc.x += pw * v4.x; acc.y += pw * v4.y;
            acc.z += pw * v4.z; acc.w += pw * v4.w;
        }
        *(float4*)(&red[w][lane*4]) = acc;
    }
    __syncthreads();

    #pragma unroll
    for (int i = 0; i < 2; ++i) {
        const int idx = tid + i*512;
        const int qq = idx >> 8, d = idx & 255;
        out[(size_t)(b*QQ + q0 + qq) * DD + d] = red[qq][d] + red[4+qq][d];
    }
}

extern "C" void kernel_launch(void* const* d_in, const int* in_sizes, int n_in,
                              void* d_out, int out_size, void* d_ws, size_t ws_size,
                              hipStream_t stream) {
    (void)in_sizes; (void)n_in; (void)out_size; (void)ws_size;
    const float* querys     = (const float*)d_in[0];
    const float* keys       = (const float*)d_in[1];
    const float* values     = (const float*)d_in[2];
    const int*   valid_lens = (const int*)d_in[3];
    const float* Wq         = (const float*)d_in[4];
    const float* Wk         = (const float*)d_in[5];
    const float* w_v        = (const float*)d_in[6];
    float* out = (float*)d_out;

    float*  qf     = (float*)d_ws;                         // 1 MB f32 (pre-scaled)
    ushort* kfeat  = (ushort*)(qf + (size_t)BB*QQ*HH);     // 4 MB bf16 (pre-scaled)
    float*  scores = (float*)(kfeat + (size_t)BB*KK*HH);   // 2 MB f32

    proj_both<<<dim3(16 + BB*KK/64, HH/64), 256, 0, stream>>>(
        querys, Wq, qf, keys, Wk, kfeat, valid_lens);
    scores_kernel<<<dim3(BB, QQ/4, KSPL), 256, 0, stream>>>(
        qf, kfeat, w_v, valid_lens, scores);
    attn_pv_kernel<<<dim3(BB, QQ/4), 512, 0, stream>>>(
        scores, values, valid_lens, out);
}

// Round 6
// 71.106 us; speedup vs baseline: 1.1273x; 1.1273x over previous
//
#include <hip/hip_runtime.h>

#define BB 16
#define QQ 64
#define KK 512
#define DD 256
#define HH 256
#define KSPL 8

#define LOG2E2 2.88539008177792681f   // 2*log2(e): exp2(LOG2E2*x) = e^{2x}

typedef unsigned int uint;
typedef unsigned short ushort;

__device__ __forceinline__ float fast_exp2(float x) {
#if __has_builtin(__builtin_amdgcn_exp2f)
    return __builtin_amdgcn_exp2f(x);
#else
    return exp2f(x);
#endif
}

__device__ __forceinline__ ushort f32_to_bf16_rtne(float x) {
    uint u = __float_as_uint(x);
    u = (u + 0x7FFFu + ((u >> 16) & 1u)) >> 16;
    return (ushort)u;
}

// unpack 8 bf16 (uint4) -> two float4
__device__ __forceinline__ void cvt8(uint4 u, float4& a, float4& b) {
    a.x = __uint_as_float(u.x << 16); a.y = __uint_as_float(u.x & 0xFFFF0000u);
    a.z = __uint_as_float(u.y << 16); a.w = __uint_as_float(u.y & 0xFFFF0000u);
    b.x = __uint_as_float(u.z << 16); b.y = __uint_as_float(u.z & 0xFFFF0000u);
    b.z = __uint_as_float(u.w << 16); b.w = __uint_as_float(u.w & 0xFFFF0000u);
}

// ---------------------------------------------------------------------------
// Both projections, one launch. q-features -> f32 (1MB); k-features -> bf16
// (4MB). Both pre-scaled by 2log2e. Fully-masked key tiles skipped.
// ---------------------------------------------------------------------------
__global__ __launch_bounds__(256) void proj_both(
        const float* __restrict__ Xq, const float* __restrict__ Wq, float* __restrict__ Yq,
        const float* __restrict__ Xk, const float* __restrict__ Wk, ushort* __restrict__ Yk16,
        const int* __restrict__ valid_lens) {
    __shared__ float XsT[32][68];
    __shared__ float Ws[32][64];
    const int rt = blockIdx.x;
    const bool is_q = (rt < 16);
    const float* X; const float* W; int row0;
    if (is_q) { X = Xq; W = Wq; row0 = rt * 64; }
    else {
        X = Xk; W = Wk; row0 = (rt - 16) * 64;
        const int bb    = row0 >> 9;
        const int local = row0 & 511;
        if (local >= valid_lens[bb]) return;
    }
    const int col0 = blockIdx.y * 64;
    const int tid = threadIdx.x;
    const int tx = tid & 15, ty = tid >> 4;

    float acc[4][4] = {};

    for (int k0 = 0; k0 < HH; k0 += 32) {
        {
            const int m  = tid >> 3;
            const int kk = (tid & 7) * 4;
            #pragma unroll
            for (int s = 0; s < 2; ++s) {
                float4 x4 = *(const float4*)(X + (size_t)(row0 + m + 32*s) * HH + k0 + kk);
                XsT[kk+0][m+32*s] = x4.x;
                XsT[kk+1][m+32*s] = x4.y;
                XsT[kk+2][m+32*s] = x4.z;
                XsT[kk+3][m+32*s] = x4.w;
            }
        }
        {
            const int kk = tid >> 4;
            const int c  = (tid & 15) * 4;
            #pragma unroll
            for (int s = 0; s < 2; ++s) {
                float4 w4 = *(const float4*)(W + (size_t)(k0 + kk + 16*s) * HH + col0 + c);
                *(float4*)(&Ws[kk+16*s][c]) = w4;
            }
        }
        __syncthreads();
        #pragma unroll
        for (int kk = 0; kk < 32; ++kk) {
            float4 a = *(const float4*)(&XsT[kk][ty*4]);
            float4 b = *(const float4*)(&Ws[kk][tx*4]);
            acc[0][0] += a.x*b.x; acc[0][1] += a.x*b.y; acc[0][2] += a.x*b.z; acc[0][3] += a.x*b.w;
            acc[1][0] += a.y*b.x; acc[1][1] += a.y*b.y; acc[1][2] += a.y*b.z; acc[1][3] += a.y*b.w;
            acc[2][0] += a.z*b.x; acc[2][1] += a.z*b.y; acc[2][2] += a.z*b.z; acc[2][3] += a.z*b.w;
            acc[3][0] += a.w*b.x; acc[3][1] += a.w*b.y; acc[3][2] += a.w*b.z; acc[3][3] += a.w*b.w;
        }
        __syncthreads();
    }
    if (is_q) {
        float* Y = (float*)Yq;
        #pragma unroll
        for (int i = 0; i < 4; ++i) {
            float4 o = make_float4(acc[i][0]*LOG2E2, acc[i][1]*LOG2E2,
                                   acc[i][2]*LOG2E2, acc[i][3]*LOG2E2);
            *(float4*)(Y + (size_t)(row0 + ty*4 + i) * HH + col0 + tx*4) = o;
        }
    } else {
        #pragma unroll
        for (int i = 0; i < 4; ++i) {
            ushort4 o;
            o.x = f32_to_bf16_rtne(acc[i][0]*LOG2E2);
            o.y = f32_to_bf16_rtne(acc[i][1]*LOG2E2);
            o.z = f32_to_bf16_rtne(acc[i][2]*LOG2E2);
            o.w = f32_to_bf16_rtne(acc[i][3]*LOG2E2);
            *(ushort4*)(Yk16 + (size_t)(row0 + ty*4 + i) * HH + col0 + tx*4) = o;
        }
    }
}

// ---------------------------------------------------------------------------
// scores for 4 q rows per block; kfeat in bf16; vl skip + prefetch.
// grid (B, Q/4, KSPL=8), 256 thr (4 waves). Wave strip = 16 k = 4 groups of 4.
// ---------------------------------------------------------------------------
__global__ __launch_bounds__(256) void scores_kernel(
        const float* __restrict__ qf, const ushort* __restrict__ kf16,
        const float* __restrict__ w_v, const int* __restrict__ valid_lens,
        float* __restrict__ scores) {
    const int b    = blockIdx.x;
    const int q0   = blockIdx.y * 4;
    const int ks   = blockIdx.z;
    const int lane = threadIdx.x & 63;
    const int wave = threadIdx.x >> 6;
    const int hg   = lane & 15;
    const int ksub = lane >> 4;
    const int h0   = hg * 16;

    float4 nw[4];
    float wvsum = 0.f;
    #pragma unroll
    for (int i = 0; i < 4; ++i) {
        float4 w = *(const float4*)(w_v + h0 + i*4);
        wvsum += ((w.x + w.y) + (w.z + w.w));
        nw[i] = make_float4(-2.f*w.x, -2.f*w.y, -2.f*w.z, -2.f*w.w);
    }

    float4 qv[4][4];
    #pragma unroll
    for (int r = 0; r < 4; ++r) {
        const float* qr = qf + (size_t)(b*QQ + q0 + r) * HH + h0;
        #pragma unroll
        for (int i = 0; i < 4; ++i) qv[r][i] = *(const float4*)(qr + i*4);
    }

    const int vl   = valid_lens[b];
    const int base = ks * (KK/KSPL) + wave * 16;
    int rem = vl - base;
    const int ng = (rem <= 0) ? 0 : ((rem >= 16) ? 4 : ((rem + 3) >> 2));

    float* srow0 = scores + (size_t)(b*QQ + q0) * KK;
    const ushort* kptr = kf16 + (size_t)(b*KK + base + ksub) * HH + h0;

    uint4 c0, c1;
    if (ng > 0) {
        c0 = *(const uint4*)(kptr);
        c1 = *(const uint4*)(kptr + 8);
    }

    for (int g = 0; g < ng; ++g) {
        uint4 n0, n1;
        const bool more = (g + 1 < ng);
        if (more) {
            const ushort* kp = kptr + (size_t)(g+1) * 4 * HH;
            n0 = *(const uint4*)(kp);
            n1 = *(const uint4*)(kp + 8);
        }
        float4 kv[4];
        cvt8(c0, kv[0], kv[1]);
        cvt8(c1, kv[2], kv[3]);

        float s[4];
        #pragma unroll
        for (int r = 0; r < 4; ++r) {
            float a0 = wvsum, a1 = 0.f, a2 = 0.f, a3 = 0.f;
            #pragma unroll
            for (int i = 0; i < 4; ++i) {
                float e0 = fast_exp2(qv[r][i].x + kv[i].x);
                float e1 = fast_exp2(qv[r][i].y + kv[i].y);
                float e2 = fast_exp2(qv[r][i].z + kv[i].z);
                float e3 = fast_exp2(qv[r][i].w + kv[i].w);
                a0 = fmaf(nw[i].x, __builtin_amdgcn_rcpf(e0 + 1.f), a0);
                a1 = fmaf(nw[i].y, __builtin_amdgcn_rcpf(e1 + 1.f), a1);
                a2 = fmaf(nw[i].z, __builtin_amdgcn_rcpf(e2 + 1.f), a2);
                a3 = fmaf(nw[i].w, __builtin_amdgcn_rcpf(e3 + 1.f), a3);
            }
            s[r] = (a0 + a1) + (a2 + a3);
        }
        #pragma unroll
        for (int off = 8; off; off >>= 1) {
            #pragma unroll
            for (int r = 0; r < 4; ++r) s[r] += __shfl_xor(s[r], off);
        }
        const int k = base + g*4 + ksub;
        if (hg == 0) {
            const bool ok = (k < vl);
            #pragma unroll
            for (int r = 0; r < 4; ++r)
                srow0[(size_t)r * KK + k] = ok ? s[r] : -1e6f;
        }
        c0 = n0; c1 = n1;
    }
    for (int g = ng; g < 4; ++g) {
        const int k = base + g*4 + ksub;
        if (hg == 0) {
            #pragma unroll
            for (int r = 0; r < 4; ++r) srow0[(size_t)r * KK + k] = -1e6f;
        }
    }
}

// ---------------------------------------------------------------------------
// softmax + PV, one block per (b,q). 256 thr, 4 waves.
// Softmax: wave w owns 128 contiguous k (float2/lane), LDS cross-wave combine.
// PV: [0,vl) split into 4 contiguous balanced chunks; unroll-4 with 4
// independent accumulators to batch V-row loads; cross-wave LDS reduce.
// ---------------------------------------------------------------------------
__global__ __launch_bounds__(256) void attn_pv_kernel(
        const float* __restrict__ scores, const float* __restrict__ values,
        const int* __restrict__ valid_lens, float* __restrict__ out) {
    __shared__ float ps[KK];        // 2 KB probs
    __shared__ float red[4][DD];    // 4 KB PV partials
    __shared__ float wred[8];
    const int b    = blockIdx.x;
    const int q    = blockIdx.y;
    const int tid  = threadIdx.x;
    const int lane = tid & 63;
    const int w    = tid >> 6;
    const int vl   = valid_lens[b];

    // ---- softmax ----
    const float* srow = scores + (size_t)(b*QQ + q) * KK;
    float2 s = *(const float2*)(srow + w*128 + lane*2);
    float m = fmaxf(s.x, s.y);
    #pragma unroll
    for (int off = 32; off; off >>= 1) m = fmaxf(m, __shfl_xor(m, off));
    if (lane == 0) wred[w] = m;
    __syncthreads();
    m = fmaxf(fmaxf(wred[0], wred[1]), fmaxf(wred[2], wred[3]));

    float e0 = __expf(s.x - m), e1 = __expf(s.y - m);
    float sum = e0 + e1;
    #pragma unroll
    for (int off = 32; off; off >>= 1) sum += __shfl_xor(sum, off);
    if (lane == 0) wred[4 + w] = sum;
    __syncthreads();
    sum = (wred[4] + wred[5]) + (wred[6] + wred[7]);
    const float inv = 1.f / sum;
    *(float2*)(&ps[w*128 + lane*2]) = make_float2(e0*inv, e1*inv);
    __syncthreads();

    // ---- PV: contiguous balanced chunks ----
    {
        const int c  = (vl + 3) >> 2;
        const int lo = w * c;
        int hi = lo + c; hi = (hi > vl) ? vl : hi;

        const float* V = values + (size_t)b * KK * DD + lane*4;
        float4 a0 = make_float4(0.f,0.f,0.f,0.f), a1 = a0, a2 = a0, a3 = a0;

        int k = lo;
        for (; k + 4 <= hi; k += 4) {
            const float p0 = ps[k],   p1 = ps[k+1];
            const float p2 = ps[k+2], p3 = ps[k+3];
            float4 v0 = *(const float4*)(V + (size_t)(k+0) * DD);
            float4 v1 = *(const float4*)(V + (size_t)(k+1) * DD);
            float4 v2 = *(const float4*)(V + (size_t)(k+2) * DD);
            float4 v3 = *(const float4*)(V + (size_t)(k+3) * DD);
            a0.x += p0*v0.x; a0.y += p0*v0.y; a0.z += p0*v0.z; a0.w += p0*v0.w;
            a1.x += p1*v1.x; a1.y += p1*v1.y; a1.z += p1*v1.z; a1.w += p1*v1.w;
            a2.x += p2*v2.x; a2.y += p2*v2.y; a2.z += p2*v2.z; a2.w += p2*v2.w;
            a3.x += p3*v3.x; a3.y += p3*v3.y; a3.z += p3*v3.z; a3.w += p3*v3.w;
        }
        for (; k < hi; ++k) {
            const float pw = ps[k];
            float4 v4 = *(const float4*)(V + (size_t)k * DD);
            a0.x += pw*v4.x; a0.y += pw*v4.y; a0.z += pw*v4.z; a0.w += pw*v4.w;
        }
        float4 acc;
        acc.x = (a0.x + a1.x) + (a2.x + a3.x);
        acc.y = (a0.y + a1.y) + (a2.y + a3.y);
        acc.z = (a0.z + a1.z) + (a2.z + a3.z);
        acc.w = (a0.w + a1.w) + (a2.w + a3.w);
        *(float4*)(&red[w][lane*4]) = acc;
    }
    __syncthreads();

    const float o = (red[0][tid] + red[1][tid]) + (red[2][tid] + red[3][tid]);
    out[(size_t)(b*QQ + q) * DD + tid] = o;
}

extern "C" void kernel_launch(void* const* d_in, const int* in_sizes, int n_in,
                              void* d_out, int out_size, void* d_ws, size_t ws_size,
                              hipStream_t stream) {
    (void)in_sizes; (void)n_in; (void)out_size; (void)ws_size;
    const float* querys     = (const float*)d_in[0];
    const float* keys       = (const float*)d_in[1];
    const float* values     = (const float*)d_in[2];
    const int*   valid_lens = (const int*)d_in[3];
    const float* Wq         = (const float*)d_in[4];
    const float* Wk         = (const float*)d_in[5];
    const float* w_v        = (const float*)d_in[6];
    float* out = (float*)d_out;

    float*  qf     = (float*)d_ws;                         // 1 MB f32 (pre-scaled)
    ushort* kfeat  = (ushort*)(qf + (size_t)BB*QQ*HH);     // 4 MB bf16 (pre-scaled)
    float*  scores = (float*)(kfeat + (size_t)BB*KK*HH);   // 2 MB f32

    proj_both<<<dim3(16 + BB*KK/64, HH/64), 256, 0, stream>>>(
        querys, Wq, qf, keys, Wk, kfeat, valid_lens);
    scores_kernel<<<dim3(BB, QQ/4, KSPL), 256, 0, stream>>>(
        qf, kfeat, w_v, valid_lens, scores);
    attn_pv_kernel<<<dim3(BB, QQ), 256, 0, stream>>>(
        scores, values, valid_lens, out);
}

// Round 7
// 69.757 us; speedup vs baseline: 1.1491x; 1.0193x over previous
//
#include <hip/hip_runtime.h>

#define BB 16
#define QQ 64
#define KK 512
#define DD 256
#define HH 256

#define LOG2E2 2.88539008177792681f   // 2*log2(e): exp2(LOG2E2*x) = e^{2x}

typedef unsigned int uint;
typedef unsigned short ushort;

__device__ __forceinline__ float fast_exp2(float x) {
#if __has_builtin(__builtin_amdgcn_exp2f)
    return __builtin_amdgcn_exp2f(x);
#else
    return exp2f(x);
#endif
}

__device__ __forceinline__ ushort f32_to_bf16_rtne(float x) {
    uint u = __float_as_uint(x);
    u = (u + 0x7FFFu + ((u >> 16) & 1u)) >> 16;
    return (ushort)u;
}

// unpack 8 bf16 (uint4) -> two float4
__device__ __forceinline__ void cvt8(uint4 u, float4& a, float4& b) {
    a.x = __uint_as_float(u.x << 16); a.y = __uint_as_float(u.x & 0xFFFF0000u);
    a.z = __uint_as_float(u.y << 16); a.w = __uint_as_float(u.y & 0xFFFF0000u);
    b.x = __uint_as_float(u.z << 16); b.y = __uint_as_float(u.z & 0xFFFF0000u);
    b.z = __uint_as_float(u.w << 16); b.w = __uint_as_float(u.w & 0xFFFF0000u);
}

// ---------------------------------------------------------------------------
// Both projections, one launch. q-features -> f32 (1MB); k-features -> bf16
// (4MB). Both pre-scaled by 2log2e. Fully-masked key tiles skipped.
// ---------------------------------------------------------------------------
__global__ __launch_bounds__(256) void proj_both(
        const float* __restrict__ Xq, const float* __restrict__ Wq, float* __restrict__ Yq,
        const float* __restrict__ Xk, const float* __restrict__ Wk, ushort* __restrict__ Yk16,
        const int* __restrict__ valid_lens) {
    __shared__ float XsT[32][68];
    __shared__ float Ws[32][64];
    const int rt = blockIdx.x;
    const bool is_q = (rt < 16);
    const float* X; const float* W; int row0;
    if (is_q) { X = Xq; W = Wq; row0 = rt * 64; }
    else {
        X = Xk; W = Wk; row0 = (rt - 16) * 64;
        const int bb    = row0 >> 9;
        const int local = row0 & 511;
        if (local >= valid_lens[bb]) return;
    }
    const int col0 = blockIdx.y * 64;
    const int tid = threadIdx.x;
    const int tx = tid & 15, ty = tid >> 4;

    float acc[4][4] = {};

    for (int k0 = 0; k0 < HH; k0 += 32) {
        {
            const int m  = tid >> 3;
            const int kk = (tid & 7) * 4;
            #pragma unroll
            for (int s = 0; s < 2; ++s) {
                float4 x4 = *(const float4*)(X + (size_t)(row0 + m + 32*s) * HH + k0 + kk);
                XsT[kk+0][m+32*s] = x4.x;
                XsT[kk+1][m+32*s] = x4.y;
                XsT[kk+2][m+32*s] = x4.z;
                XsT[kk+3][m+32*s] = x4.w;
            }
        }
        {
            const int kk = tid >> 4;
            const int c  = (tid & 15) * 4;
            #pragma unroll
            for (int s = 0; s < 2; ++s) {
                float4 w4 = *(const float4*)(W + (size_t)(k0 + kk + 16*s) * HH + col0 + c);
                *(float4*)(&Ws[kk+16*s][c]) = w4;
            }
        }
        __syncthreads();
        #pragma unroll
        for (int kk = 0; kk < 32; ++kk) {
            float4 a = *(const float4*)(&XsT[kk][ty*4]);
            float4 b = *(const float4*)(&Ws[kk][tx*4]);
            acc[0][0] += a.x*b.x; acc[0][1] += a.x*b.y; acc[0][2] += a.x*b.z; acc[0][3] += a.x*b.w;
            acc[1][0] += a.y*b.x; acc[1][1] += a.y*b.y; acc[1][2] += a.y*b.z; acc[1][3] += a.y*b.w;
            acc[2][0] += a.z*b.x; acc[2][1] += a.z*b.y; acc[2][2] += a.z*b.z; acc[2][3] += a.z*b.w;
            acc[3][0] += a.w*b.x; acc[3][1] += a.w*b.y; acc[3][2] += a.w*b.z; acc[3][3] += a.w*b.w;
        }
        __syncthreads();
    }
    if (is_q) {
        float* Y = (float*)Yq;
        #pragma unroll
        for (int i = 0; i < 4; ++i) {
            float4 o = make_float4(acc[i][0]*LOG2E2, acc[i][1]*LOG2E2,
                                   acc[i][2]*LOG2E2, acc[i][3]*LOG2E2);
            *(float4*)(Y + (size_t)(row0 + ty*4 + i) * HH + col0 + tx*4) = o;
        }
    } else {
        #pragma unroll
        for (int i = 0; i < 4; ++i) {
            ushort4 o;
            o.x = f32_to_bf16_rtne(acc[i][0]*LOG2E2);
            o.y = f32_to_bf16_rtne(acc[i][1]*LOG2E2);
            o.z = f32_to_bf16_rtne(acc[i][2]*LOG2E2);
            o.w = f32_to_bf16_rtne(acc[i][3]*LOG2E2);
            *(ushort4*)(Yk16 + (size_t)(row0 + ty*4 + i) * HH + col0 + tx*4) = o;
        }
    }
}

// ---------------------------------------------------------------------------
// Fused scores + masked softmax + PV. One block per (b,q): 256 thr, 4 waves.
// Scores: [0,vl) split into 4 vl-balanced contiguous strips (one per wave);
// wave step = 4 k (ksub=lane>>4), lane owns 16 h (hg=lane&15); scores -> LDS
// (pre-init -1e6 = mask). Softmax: 4 waves x 128 k, LDS combine. PV: same
// balanced strips, unroll-4, 4 independent accumulators; LDS cross-wave
// reduce.
// ---------------------------------------------------------------------------
__global__ __launch_bounds__(256) void fused_attn(
        const float* __restrict__ qf, const ushort* __restrict__ kf16,
        const float* __restrict__ w_v, const int* __restrict__ valid_lens,
        const float* __restrict__ values, float* __restrict__ out) {
    __shared__ float sc[KK];        // 2 KB scores -> probs
    __shared__ float red[4][DD];    // 4 KB PV partials
    __shared__ float wred[8];
    const int b    = blockIdx.x;
    const int q    = blockIdx.y;
    const int tid  = threadIdx.x;
    const int lane = tid & 63;
    const int w    = tid >> 6;
    const int hg   = lane & 15;
    const int ksub = lane >> 4;
    const int h0   = hg * 16;
    const int vl   = valid_lens[b];

    sc[tid]       = -1e6f;
    sc[tid + 256] = -1e6f;

    float4 nw[4];
    float wvsum = 0.f;
    #pragma unroll
    for (int i = 0; i < 4; ++i) {
        float4 wv4 = *(const float4*)(w_v + h0 + i*4);
        wvsum += ((wv4.x + wv4.y) + (wv4.z + wv4.w));
        nw[i] = make_float4(-2.f*wv4.x, -2.f*wv4.y, -2.f*wv4.z, -2.f*wv4.w);
    }
    float4 qv[4];
    {
        const float* qr = qf + (size_t)(b*QQ + q) * HH + h0;
        #pragma unroll
        for (int i = 0; i < 4; ++i) qv[i] = *(const float4*)(qr + i*4);
    }

    // balanced strip for this wave
    const int c  = (vl + 3) >> 2;
    const int lo = w * c;
    int hi = lo + c; hi = (hi > vl) ? vl : hi;
    const int cnt = hi - lo;
    const int ng  = (cnt <= 0) ? 0 : ((cnt + 3) >> 2);

    __syncthreads();   // sc init visible

    // ---- Phase A: scores ----
    {
        const size_t brows = (size_t)b * KK;
        auto rowptr = [&](int g) -> const ushort* {
            int row = lo + g*4 + ksub;
            row = (row < vl) ? row : (vl - 1);     // clamp: stay in written rows
            return kf16 + (brows + row) * HH + h0;
        };
        uint4 c0, c1;
        if (ng > 0) {
            const ushort* p = rowptr(0);
            c0 = *(const uint4*)(p);
            c1 = *(const uint4*)(p + 8);
        }
        for (int g = 0; g < ng; ++g) {
            uint4 n0, n1;
            const bool more = (g + 1 < ng);
            if (more) {
                const ushort* p = rowptr(g + 1);
                n0 = *(const uint4*)(p);
                n1 = *(const uint4*)(p + 8);
            }
            float4 kv[4];
            cvt8(c0, kv[0], kv[1]);
            cvt8(c1, kv[2], kv[3]);

            float a0 = wvsum, a1 = 0.f, a2 = 0.f, a3 = 0.f;
            #pragma unroll
            for (int i = 0; i < 4; ++i) {
                float e0 = fast_exp2(qv[i].x + kv[i].x);
                float e1 = fast_exp2(qv[i].y + kv[i].y);
                float e2 = fast_exp2(qv[i].z + kv[i].z);
                float e3 = fast_exp2(qv[i].w + kv[i].w);
                a0 = fmaf(nw[i].x, __builtin_amdgcn_rcpf(e0 + 1.f), a0);
                a1 = fmaf(nw[i].y, __builtin_amdgcn_rcpf(e1 + 1.f), a1);
                a2 = fmaf(nw[i].z, __builtin_amdgcn_rcpf(e2 + 1.f), a2);
                a3 = fmaf(nw[i].w, __builtin_amdgcn_rcpf(e3 + 1.f), a3);
            }
            float s = (a0 + a1) + (a2 + a3);
            s += __shfl_xor(s, 8);
            s += __shfl_xor(s, 4);
            s += __shfl_xor(s, 2);
            s += __shfl_xor(s, 1);

            const int k = lo + g*4 + ksub;
            if (hg == 0 && k < hi) sc[k] = s;

            if (more) { c0 = n0; c1 = n1; }
        }
    }
    __syncthreads();

    // ---- Phase B: masked softmax over 512 (invalid = -1e6 -> exp 0) ----
    {
        float2 s2 = *(const float2*)(&sc[w*128 + lane*2]);
        float m = fmaxf(s2.x, s2.y);
        #pragma unroll
        for (int off = 32; off; off >>= 1) m = fmaxf(m, __shfl_xor(m, off));
        if (lane == 0) wred[w] = m;
        __syncthreads();
        m = fmaxf(fmaxf(wred[0], wred[1]), fmaxf(wred[2], wred[3]));

        float e0 = __expf(s2.x - m), e1 = __expf(s2.y - m);
        float sum = e0 + e1;
        #pragma unroll
        for (int off = 32; off; off >>= 1) sum += __shfl_xor(sum, off);
        if (lane == 0) wred[4 + w] = sum;
        __syncthreads();
        sum = (wred[4] + wred[5]) + (wred[6] + wred[7]);
        const float inv = 1.f / sum;
        *(float2*)(&sc[w*128 + lane*2]) = make_float2(e0*inv, e1*inv);
    }
    __syncthreads();

    // ---- Phase C: PV over the same balanced strip ----
    {
        const float* V = values + (size_t)b * KK * DD + lane*4;
        float4 a0 = make_float4(0.f,0.f,0.f,0.f), a1 = a0, a2 = a0, a3 = a0;

        int k = lo;
        for (; k + 4 <= hi; k += 4) {
            const float p0 = sc[k],   p1 = sc[k+1];
            const float p2 = sc[k+2], p3 = sc[k+3];
            float4 v0 = *(const float4*)(V + (size_t)(k+0) * DD);
            float4 v1 = *(const float4*)(V + (size_t)(k+1) * DD);
            float4 v2 = *(const float4*)(V + (size_t)(k+2) * DD);
            float4 v3 = *(const float4*)(V + (size_t)(k+3) * DD);
            a0.x += p0*v0.x; a0.y += p0*v0.y; a0.z += p0*v0.z; a0.w += p0*v0.w;
            a1.x += p1*v1.x; a1.y += p1*v1.y; a1.z += p1*v1.z; a1.w += p1*v1.w;
            a2.x += p2*v2.x; a2.y += p2*v2.y; a2.z += p2*v2.z; a2.w += p2*v2.w;
            a3.x += p3*v3.x; a3.y += p3*v3.y; a3.z += p3*v3.z; a3.w += p3*v3.w;
        }
        for (; k < hi; ++k) {
            const float pw = sc[k];
            float4 v4 = *(const float4*)(V + (size_t)k * DD);
            a0.x += pw*v4.x; a0.y += pw*v4.y; a0.z += pw*v4.z; a0.w += pw*v4.w;
        }
        float4 acc;
        acc.x = (a0.x + a1.x) + (a2.x + a3.x);
        acc.y = (a0.y + a1.y) + (a2.y + a3.y);
        acc.z = (a0.z + a1.z) + (a2.z + a3.z);
        acc.w = (a0.w + a1.w) + (a2.w + a3.w);
        *(float4*)(&red[w][lane*4]) = acc;
    }
    __syncthreads();

    const float o = (red[0][tid] + red[1][tid]) + (red[2][tid] + red[3][tid]);
    out[(size_t)(b*QQ + q) * DD + tid] = o;
}

extern "C" void kernel_launch(void* const* d_in, const int* in_sizes, int n_in,
                              void* d_out, int out_size, void* d_ws, size_t ws_size,
                              hipStream_t stream) {
    (void)in_sizes; (void)n_in; (void)out_size; (void)ws_size;
    const float* querys     = (const float*)d_in[0];
    const float* keys       = (const float*)d_in[1];
    const float* values     = (const float*)d_in[2];
    const int*   valid_lens = (const int*)d_in[3];
    const float* Wq         = (const float*)d_in[4];
    const float* Wk         = (const float*)d_in[5];
    const float* w_v        = (const float*)d_in[6];
    float* out = (float*)d_out;

    float*  qf    = (float*)d_ws;                         // 1 MB f32 (pre-scaled)
    ushort* kfeat = (ushort*)(qf + (size_t)BB*QQ*HH);     // 4 MB bf16 (pre-scaled)

    proj_both<<<dim3(16 + BB*KK/64, HH/64), 256, 0, stream>>>(
        querys, Wq, qf, keys, Wk, kfeat, valid_lens);
    fused_attn<<<dim3(BB, QQ), 256, 0, stream>>>(
        qf, kfeat, w_v, valid_lens, values, out);
}